// Round 1
// baseline (293.034 us; speedup 1.0000x reference)
//
#include <hip/hip_runtime.h>
#include <stdint.h>

typedef unsigned short u16;
typedef __bf16 bf16x8 __attribute__((ext_vector_type(8)));
typedef float f32x4 __attribute__((ext_vector_type(4)));

// Problem constants: B=1, S=128, L=384, D=256, H=8, hd=32
#define NROWS    49152      // S*L = 128*384
#define MSA_N    12582912   // NROWS*256
#define QKV_OFF  12582912   // elements per Q/K/V buffer

__device__ __forceinline__ u16 f2bf(float x) {
    unsigned int u = __float_as_uint(x);
    u += 0x7fffu + ((u >> 16) & 1u);
    return (u16)(u >> 16);
}
__device__ __forceinline__ float bf2f(u16 h) {
    return __uint_as_float(((unsigned int)h) << 16);
}

// ---------------------------------------------------------------- convert msa
__global__ void convert_msa(const float* __restrict__ src, u16* __restrict__ dst) {
    int i = blockIdx.x * 256 + threadIdx.x;     // 12288 blocks * 256 * 4 floats
    float4 v = ((const float4*)src)[i];
    ushort4 o;
    o.x = f2bf(v.x); o.y = f2bf(v.y); o.z = f2bf(v.z); o.w = f2bf(v.w);
    ((ushort4*)dst)[i] = o;
}

// ---------------------------------------------------------------- pack weights
// Wqkv rows: [0,256)=Wq, [256,512)=Wk, [512,768)=Wv  (row-major, K contiguous)
// Wo split into hi/lo bf16 for the compensated output projection.
__global__ void pack_weights(const float* __restrict__ Wq, const float* __restrict__ Wk,
                             const float* __restrict__ Wv, const float* __restrict__ Wo,
                             u16* __restrict__ Wqkv, u16* __restrict__ Woh, u16* __restrict__ Wol) {
    int i = blockIdx.x * 256 + threadIdx.x;     // 256 blocks -> 65536
    Wqkv[i]           = f2bf(Wq[i]);
    Wqkv[65536 + i]   = f2bf(Wk[i]);
    Wqkv[131072 + i]  = f2bf(Wv[i]);
    float w = Wo[i];
    u16 hi = f2bf(w);
    Woh[i] = hi;
    Wol[i] = f2bf(w - bf2f(hi));
}

// ---------------------------------------------------------------- QKV GEMM
// C[49152 x 768] = msa_bf16[49152 x 256] * Wqkv^T[768 x 256]
// epilogue scatters into Qkv[which][s][h][l][d] (bf16) for the attention kernel.
__launch_bounds__(256, 2)
__global__ void qkv_gemm(const u16* __restrict__ A, const u16* __restrict__ W,
                         u16* __restrict__ Qkv) {
    __shared__ __align__(16) u16 As[128 * 32];
    __shared__ __align__(16) u16 Bs[128 * 32];
    const int tid = threadIdx.x;
    const int tm = blockIdx.x % 384, tn = blockIdx.x / 384;  // grid 2304
    const int lane = tid & 63, wave = tid >> 6;
    const int lm = lane & 15, lq = lane >> 4;
    const int wm = (wave >> 1) * 64, wn = (wave & 1) * 64;
    f32x4 acc[4][4] = {};

    const int ra = tid >> 2, ka = (tid & 3) << 3;
    const int rb = (tid + 256) >> 2;            // kb == ka

    for (int k0 = 0; k0 < 256; k0 += 32) {
        *(uint4*)&As[ra * 32 + ka] = *(const uint4*)&A[(tm * 128 + ra) * 256 + k0 + ka];
        *(uint4*)&As[rb * 32 + ka] = *(const uint4*)&A[(tm * 128 + rb) * 256 + k0 + ka];
        *(uint4*)&Bs[ra * 32 + ka] = *(const uint4*)&W[(tn * 128 + ra) * 256 + k0 + ka];
        *(uint4*)&Bs[rb * 32 + ka] = *(const uint4*)&W[(tn * 128 + rb) * 256 + k0 + ka];
        __syncthreads();
        bf16x8 af[4], bfr[4];
        #pragma unroll
        for (int i = 0; i < 4; ++i)
            af[i] = *(const bf16x8*)&As[(wm + i * 16 + lm) * 32 + lq * 8];
        #pragma unroll
        for (int j = 0; j < 4; ++j)
            bfr[j] = *(const bf16x8*)&Bs[(wn + j * 16 + lm) * 32 + lq * 8];
        #pragma unroll
        for (int i = 0; i < 4; ++i)
            #pragma unroll
            for (int j = 0; j < 4; ++j)
                acc[i][j] = __builtin_amdgcn_mfma_f32_16x16x32_bf16(af[i], bfr[j], acc[i][j], 0, 0, 0);
        __syncthreads();
    }
    // epilogue: C/D layout col=lane&15, row=(lane>>4)*4+reg
    #pragma unroll
    for (int i = 0; i < 4; ++i) {
        #pragma unroll
        for (int j = 0; j < 4; ++j) {
            #pragma unroll
            for (int r = 0; r < 4; ++r) {
                int R = tm * 128 + wm + i * 16 + lq * 4 + r;     // row in [0,49152)
                int C = tn * 128 + wn + j * 16 + lm;             // col in [0,768)
                int s = R / 384, l = R - s * 384;
                int which = C >> 8, h = (C >> 5) & 7, d = C & 31;
                Qkv[which * QKV_OFF + (((s << 3) + h) * 384 + l) * 32 + d] = f2bf(acc[i][j][r]);
            }
        }
    }
}

// ---------------------------------------------------------------- attention
// One block per (s,h). K[384][32] and V^T[32][392-padded] in LDS, Q frag in regs.
// Max-free softmax (logits bounded ~0.6), P via per-wave LDS scratch (stride 36).
__launch_bounds__(256, 2)
__global__ void msa_attention(const u16* __restrict__ Qkv,
                              u16* __restrict__ Ahi, u16* __restrict__ Alo) {
    __shared__ __align__(16) u16 Ks[384 * 32];          // 24576 B
    __shared__ __align__(16) u16 Vt[31 * 392 + 384];    // 25072 B, row stride 392
    __shared__ __align__(16) u16 Ps[4][572];            // per-wave 16x(32, stride 36); 4576 B
    const int tid = threadIdx.x;
    const int sh = blockIdx.x;                           // 1024 blocks
    const int s = sh >> 3, h = sh & 7;
    const u16* Qg = Qkv + (size_t)sh * 12288;
    const u16* Kg = Qg + QKV_OFF;
    const u16* Vg = Qg + 2 * QKV_OFF;

    for (int i = tid; i < 1536; i += 256)
        *(uint4*)&Ks[i * 8] = *(const uint4*)&Kg[i * 8];
    for (int i = tid; i < 1536; i += 256) {
        int m = i >> 2, d0 = (i & 3) << 3;
        uint4 v = *(const uint4*)&Vg[i * 8];
        unsigned int p[4] = {v.x, v.y, v.z, v.w};
        #pragma unroll
        for (int jj = 0; jj < 4; ++jj) {
            Vt[(d0 + 2 * jj) * 392 + m]     = (u16)(p[jj] & 0xffffu);
            Vt[(d0 + 2 * jj + 1) * 392 + m] = (u16)(p[jj] >> 16);
        }
    }
    __syncthreads();

    const int lane = tid & 63, wave = tid >> 6;
    const int lm = lane & 15, lq = lane >> 4;
    const float CEXP = 0.17677669529663687f * 1.4426950408889634f;  // SCALE*log2(e)
    u16* pw = &Ps[wave][0];

    union Frag { bf16x8 v; struct { uint2 a, b; } u; };

    for (int it = 0; it < 6; ++it) {
        const int l0 = (it * 4 + wave) * 16;
        bf16x8 aq = *(const bf16x8*)&Qg[(l0 + lm) * 32 + lq * 8];
        f32x4 o0 = {}, o1 = {};
        float ls[4] = {0.f, 0.f, 0.f, 0.f};
        for (int n0 = 0; n0 < 384; n0 += 32) {
            bf16x8 bk0 = *(const bf16x8*)&Ks[(n0 + lm) * 32 + lq * 8];
            bf16x8 bk1 = *(const bf16x8*)&Ks[(n0 + 16 + lm) * 32 + lq * 8];
            f32x4 z = {};
            f32x4 s0 = __builtin_amdgcn_mfma_f32_16x16x32_bf16(aq, bk0, z, 0, 0, 0);
            f32x4 s1 = __builtin_amdgcn_mfma_f32_16x16x32_bf16(aq, bk1, z, 0, 0, 0);
            #pragma unroll
            for (int r = 0; r < 4; ++r) {
                float p0 = exp2f(s0[r] * CEXP);
                float p1 = exp2f(s1[r] * CEXP);
                ls[r] += p0 + p1;
                pw[(lq * 4 + r) * 36 + lm]      = f2bf(p0);   // P in (row,col), stride 36
                pw[(lq * 4 + r) * 36 + 16 + lm] = f2bf(p1);
            }
            asm volatile("s_waitcnt lgkmcnt(0)" ::: "memory");
            Frag ap;
            ap.u.a = *(const uint2*)&pw[lm * 36 + lq * 8];
            ap.u.b = *(const uint2*)&pw[lm * 36 + lq * 8 + 4];
            bf16x8 bv0 = *(const bf16x8*)&Vt[lm * 392 + n0 + lq * 8];
            bf16x8 bv1 = *(const bf16x8*)&Vt[(16 + lm) * 392 + n0 + lq * 8];
            o0 = __builtin_amdgcn_mfma_f32_16x16x32_bf16(ap.v, bv0, o0, 0, 0, 0);
            o1 = __builtin_amdgcn_mfma_f32_16x16x32_bf16(ap.v, bv1, o1, 0, 0, 0);
        }
        #pragma unroll
        for (int r = 0; r < 4; ++r) {
            float L = ls[r];
            L += __shfl_xor(L, 1);
            L += __shfl_xor(L, 2);
            L += __shfl_xor(L, 4);
            L += __shfl_xor(L, 8);
            float inv = 1.0f / L;
            float x0 = o0[r] * inv, x1 = o1[r] * inv;
            int Arow = s * 384 + l0 + lq * 4 + r;
            int c0 = h * 32 + lm, c1 = c0 + 16;
            u16 h0 = f2bf(x0), h1 = f2bf(x1);
            Ahi[Arow * 256 + c0] = h0;
            Alo[Arow * 256 + c0] = f2bf(x0 - bf2f(h0));
            Ahi[Arow * 256 + c1] = h1;
            Alo[Arow * 256 + c1] = f2bf(x1 - bf2f(h1));
        }
    }
}

// ---------------------------------------------------------------- output GEMM (bf16x2 split)
// out[49152 x 256] = (Ah+Al) * (Wh+Wl)^T  via  Al*Wh + Ah*Wl + Ah*Wh  (fp32 out)
__launch_bounds__(256, 2)
__global__ void out_gemm(const u16* __restrict__ Ahi, const u16* __restrict__ Alo,
                         const u16* __restrict__ Woh, const u16* __restrict__ Wol,
                         float* __restrict__ out) {
    __shared__ __align__(16) u16 Ah[128 * 32], Al[128 * 32], Bh[128 * 32], Bl[128 * 32];
    const int tid = threadIdx.x;
    const int tm = blockIdx.x % 384, tn = blockIdx.x / 384;  // grid 768
    const int lane = tid & 63, wave = tid >> 6;
    const int lm = lane & 15, lq = lane >> 4;
    const int wm = (wave >> 1) * 64, wn = (wave & 1) * 64;
    f32x4 acc[4][4] = {};

    const int ra = tid >> 2, ka = (tid & 3) << 3;
    const int rb = (tid + 256) >> 2;

    for (int k0 = 0; k0 < 256; k0 += 32) {
        *(uint4*)&Ah[ra * 32 + ka] = *(const uint4*)&Ahi[(tm * 128 + ra) * 256 + k0 + ka];
        *(uint4*)&Ah[rb * 32 + ka] = *(const uint4*)&Ahi[(tm * 128 + rb) * 256 + k0 + ka];
        *(uint4*)&Al[ra * 32 + ka] = *(const uint4*)&Alo[(tm * 128 + ra) * 256 + k0 + ka];
        *(uint4*)&Al[rb * 32 + ka] = *(const uint4*)&Alo[(tm * 128 + rb) * 256 + k0 + ka];
        *(uint4*)&Bh[ra * 32 + ka] = *(const uint4*)&Woh[(tn * 128 + ra) * 256 + k0 + ka];
        *(uint4*)&Bh[rb * 32 + ka] = *(const uint4*)&Woh[(tn * 128 + rb) * 256 + k0 + ka];
        *(uint4*)&Bl[ra * 32 + ka] = *(const uint4*)&Wol[(tn * 128 + ra) * 256 + k0 + ka];
        *(uint4*)&Bl[rb * 32 + ka] = *(const uint4*)&Wol[(tn * 128 + rb) * 256 + k0 + ka];
        __syncthreads();
        bf16x8 ahf[4], alf[4], bhf[4], blf[4];
        #pragma unroll
        for (int i = 0; i < 4; ++i) {
            ahf[i] = *(const bf16x8*)&Ah[(wm + i * 16 + lm) * 32 + lq * 8];
            alf[i] = *(const bf16x8*)&Al[(wm + i * 16 + lm) * 32 + lq * 8];
        }
        #pragma unroll
        for (int j = 0; j < 4; ++j) {
            bhf[j] = *(const bf16x8*)&Bh[(wn + j * 16 + lm) * 32 + lq * 8];
            blf[j] = *(const bf16x8*)&Bl[(wn + j * 16 + lm) * 32 + lq * 8];
        }
        #pragma unroll
        for (int i = 0; i < 4; ++i)
            #pragma unroll
            for (int j = 0; j < 4; ++j) {
                acc[i][j] = __builtin_amdgcn_mfma_f32_16x16x32_bf16(alf[i], bhf[j], acc[i][j], 0, 0, 0);
                acc[i][j] = __builtin_amdgcn_mfma_f32_16x16x32_bf16(ahf[i], blf[j], acc[i][j], 0, 0, 0);
                acc[i][j] = __builtin_amdgcn_mfma_f32_16x16x32_bf16(ahf[i], bhf[j], acc[i][j], 0, 0, 0);
            }
        __syncthreads();
    }
    #pragma unroll
    for (int i = 0; i < 4; ++i)
        #pragma unroll
        for (int j = 0; j < 4; ++j)
            #pragma unroll
            for (int r = 0; r < 4; ++r) {
                int R = tm * 128 + wm + i * 16 + lq * 4 + r;
                int C = tn * 128 + wn + j * 16 + lm;
                out[R * 256 + C] = acc[i][j][r];
            }
}

// ---------------------------------------------------------------- launch
extern "C" void kernel_launch(void* const* d_in, const int* in_sizes, int n_in,
                              void* d_out, int out_size, void* d_ws, size_t ws_size,
                              hipStream_t stream) {
    const float* msa = (const float*)d_in[0];
    // d_in[1] = pair (dead code in reference), d_in[6] = Wpb (dead code)
    const float* Wq = (const float*)d_in[2];
    const float* Wk = (const float*)d_in[3];
    const float* Wv = (const float*)d_in[4];
    const float* Wo = (const float*)d_in[5];
    char* ws = (char*)d_ws;
    // workspace layout (bytes), total ~151.7 MB
    u16* msa_bf = (u16*)(ws + 0);              // 25165824
    u16* Qkv    = (u16*)(ws + 25165824);       // 75497472 (Q,K,V each 25165824)
    u16* Ahi    = (u16*)(ws + 100663296);      // 25165824
    u16* Alo    = (u16*)(ws + 125829120);      // 25165824
    u16* Wqkv   = (u16*)(ws + 150994944);      // 393216
    u16* Woh    = (u16*)(ws + 151388160);      // 131072
    u16* Wol    = (u16*)(ws + 151519232);      // 131072
    float* out  = (float*)d_out;

    hipLaunchKernelGGL(convert_msa, dim3(12288), dim3(256), 0, stream, msa, msa_bf);
    hipLaunchKernelGGL(pack_weights, dim3(256), dim3(256), 0, stream, Wq, Wk, Wv, Wo, Wqkv, Woh, Wol);
    hipLaunchKernelGGL(qkv_gemm, dim3(2304), dim3(256), 0, stream, msa_bf, Wqkv, Qkv);
    hipLaunchKernelGGL(msa_attention, dim3(1024), dim3(256), 0, stream, Qkv, Ahi, Alo);
    hipLaunchKernelGGL(out_gemm, dim3(768), dim3(256), 0, stream, Ahi, Alo, Woh, Wol, out);
}

// Round 2
// 283.639 us; speedup vs baseline: 1.0331x; 1.0331x over previous
//
#include <hip/hip_runtime.h>
#include <stdint.h>

typedef unsigned short u16;
typedef __bf16 bf16x8 __attribute__((ext_vector_type(8)));
typedef short s16x4 __attribute__((ext_vector_type(4)));
typedef float f32x4 __attribute__((ext_vector_type(4)));

#define QKV_STRIDE 12288    // per (s,h): 384 * 32

__device__ __forceinline__ u16 f2bf(float x) {
    unsigned int u = __float_as_uint(x);
    u += 0x7fffu + ((u >> 16) & 1u);
    return (u16)(u >> 16);
}
__device__ __forceinline__ float bf2f(u16 h) {
    return __uint_as_float(((unsigned int)h) << 16);
}
__device__ __forceinline__ float tbf(float x) {   // truncate to bf16 precision
    return __uint_as_float(__float_as_uint(x) & 0xffff0000u);
}

// PV matmul: 16x16x16 bf16 (P^T C-frag is directly a valid B-frag).
static __device__ __forceinline__ f32x4 pv_mfma(s16x4 a, s16x4 b, f32x4 c) {
#if __has_builtin(__builtin_amdgcn_mfma_f32_16x16x16bf16_1k)
    return __builtin_amdgcn_mfma_f32_16x16x16bf16_1k(a, b, c, 0, 0, 0);
#else
    // zero-extend k=quad*4+j frags to k=quad*8+j frags: identical result
    union { s16x4 h[2]; bf16x8 v; } ua, ub;
    s16x4 zz = {0, 0, 0, 0};
    ua.h[0] = a; ua.h[1] = zz;
    ub.h[0] = b; ub.h[1] = zz;
    return __builtin_amdgcn_mfma_f32_16x16x32_bf16(ua.v, ub.v, c, 0, 0, 0);
#endif
}

// ---------------------------------------------------------------- convert msa
__global__ void convert_msa(const float* __restrict__ src, u16* __restrict__ dst) {
    int i = blockIdx.x * 256 + threadIdx.x;
    float4 v = ((const float4*)src)[i];
    ushort4 o;
    o.x = f2bf(v.x); o.y = f2bf(v.y); o.z = f2bf(v.z); o.w = f2bf(v.w);
    ((ushort4*)dst)[i] = o;
}

// ---------------------------------------------------------------- pack weights
__global__ void pack_weights(const float* __restrict__ Wq, const float* __restrict__ Wk,
                             const float* __restrict__ Wv, const float* __restrict__ Wo,
                             u16* __restrict__ Wqkv, u16* __restrict__ Woh, u16* __restrict__ Wol) {
    int i = blockIdx.x * 256 + threadIdx.x;
    Wqkv[i]          = f2bf(Wq[i]);
    Wqkv[65536 + i]  = f2bf(Wk[i]);
    Wqkv[131072 + i] = f2bf(Wv[i]);
    float w = Wo[i];
    u16 hi = f2bf(w);
    Woh[i] = hi;
    Wol[i] = f2bf(w - bf2f(hi));
}

// ---------------------------------------------------------------- QKV GEMM
// tn<4 (Q,K): transposed orientation, packed [sh][l][d] stores (Q pre-scaled).
// tn>=4 (V): normal orientation, packed V^T [sh][d][l] stores.
__launch_bounds__(256, 2)
__global__ void qkv_gemm(const u16* __restrict__ A, const u16* __restrict__ W,
                         u16* __restrict__ Qb, u16* __restrict__ Kb, u16* __restrict__ VTb) {
    __shared__ __align__(16) u16 As[128 * 32];
    __shared__ __align__(16) u16 Bs[128 * 32];
    const int tid = threadIdx.x;
    const int tm = blockIdx.x % 384, tn = blockIdx.x / 384;   // grid 2304
    const bool trans = (tn < 4);
    const int lane = tid & 63, wave = tid >> 6;
    const int lm = lane & 15, lq = lane >> 4;
    const int wm = (wave >> 1) * 64, wn = (wave & 1) * 64;
    const float CEXPF = 0.17677669529663687f * 1.4426950408889634f;
    f32x4 acc[4][4] = {};

    const int ra = tid >> 2, ka = (tid & 3) << 3;
    const int rb = ra + 64;

    for (int k0 = 0; k0 < 256; k0 += 32) {
        *(uint4*)&As[ra * 32 + ka] = *(const uint4*)&A[(tm * 128 + ra) * 256 + k0 + ka];
        *(uint4*)&As[rb * 32 + ka] = *(const uint4*)&A[(tm * 128 + rb) * 256 + k0 + ka];
        *(uint4*)&Bs[ra * 32 + ka] = *(const uint4*)&W[(tn * 128 + ra) * 256 + k0 + ka];
        *(uint4*)&Bs[rb * 32 + ka] = *(const uint4*)&W[(tn * 128 + rb) * 256 + k0 + ka];
        __syncthreads();
        const u16* Xs = trans ? Bs : As;   // A-operand (m dim)
        const u16* Ys = trans ? As : Bs;   // B-operand (n dim)
        bf16x8 xf[4], yf[4];
        #pragma unroll
        for (int i = 0; i < 4; ++i)
            xf[i] = *(const bf16x8*)&Xs[(wm + i * 16 + lm) * 32 + lq * 8];
        #pragma unroll
        for (int j = 0; j < 4; ++j)
            yf[j] = *(const bf16x8*)&Ys[(wn + j * 16 + lm) * 32 + lq * 8];
        #pragma unroll
        for (int i = 0; i < 4; ++i)
            #pragma unroll
            for (int j = 0; j < 4; ++j)
                acc[i][j] = __builtin_amdgcn_mfma_f32_16x16x32_bf16(xf[i], yf[j], acc[i][j], 0, 0, 0);
        __syncthreads();
    }

    if (trans) {
        // m = feature F (r -> d contiguous), n = msa row R
        #pragma unroll
        for (int i = 0; i < 4; ++i) {
            int F0 = tn * 128 + wm + i * 16 + lq * 4;
            int which = F0 >> 8;                 // 0=Q, 1=K
            int h = (F0 >> 5) & 7, d0 = F0 & 31;
            u16* dst = which ? Kb : Qb;
            float scale = which ? 1.0f : CEXPF;
            #pragma unroll
            for (int j = 0; j < 4; ++j) {
                int R = tm * 128 + wn + j * 16 + lm;
                int s = R / 384, l = R - s * 384;
                ushort4 o;
                o.x = f2bf(acc[i][j][0] * scale);
                o.y = f2bf(acc[i][j][1] * scale);
                o.z = f2bf(acc[i][j][2] * scale);
                o.w = f2bf(acc[i][j][3] * scale);
                *(ushort4*)&dst[((s * 8 + h) * 384 + l) * 32 + d0] = o;
            }
        }
    } else {
        // m = msa row R (r -> l contiguous), n = feature F in [512,768)
        #pragma unroll
        for (int j = 0; j < 4; ++j) {
            int F = tn * 128 + wn + j * 16 + lm;
            int h = (F >> 5) & 7, d = F & 31;
            #pragma unroll
            for (int i = 0; i < 4; ++i) {
                int R0 = tm * 128 + wm + i * 16 + lq * 4;
                int s = R0 / 384, l0 = R0 - s * 384;
                ushort4 o;
                o.x = f2bf(acc[i][j][0]);
                o.y = f2bf(acc[i][j][1]);
                o.z = f2bf(acc[i][j][2]);
                o.w = f2bf(acc[i][j][3]);
                *(ushort4*)&VTb[((s * 8 + h) * 32 + d) * 384 + l0] = o;
            }
        }
    }
}

// ---------------------------------------------------------------- attention
// One block per (s,h). S^T = K*Q^T (C-frag of S^T == B-frag of 16x16x16 PV).
// Outer n0 loop, K/V frags hoisted; Q frags register-resident; truncation-
// rounded P with truncated-denominator cancellation (unbiased ratio).
__launch_bounds__(256, 3)
__global__ void msa_attention(const u16* __restrict__ Qb, const u16* __restrict__ Kb,
                              const u16* __restrict__ VTb,
                              u16* __restrict__ Ahi, u16* __restrict__ Alo) {
    __shared__ __align__(16) u16 Ks[384 * 32];   // 24576 B
    __shared__ __align__(16) u16 Vt[32 * 392];   // 25088 B (V^T rows, stride 392)
    const int tid = threadIdx.x;
    const int sh = blockIdx.x;                    // 1024 blocks
    const int s = sh >> 3, h = sh & 7;
    const u16* Qg = Qb + (size_t)sh * QKV_STRIDE;
    const u16* Kg = Kb + (size_t)sh * QKV_STRIDE;
    const u16* Vg = VTb + (size_t)sh * QKV_STRIDE;

    for (int i = tid; i < 1536; i += 256)
        *(uint4*)&Ks[i * 8] = *(const uint4*)&Kg[i * 8];
    for (int i = tid; i < 1536; i += 256) {
        int d = i / 48, c = i - d * 48;
        *(uint4*)&Vt[d * 392 + c * 8] = *(const uint4*)&Vg[d * 384 + c * 8];
    }

    const int lane = tid & 63, wave = tid >> 6;
    const int lm = lane & 15, lq = lane >> 4;

    bf16x8 aq[6];
    #pragma unroll
    for (int it = 0; it < 6; ++it)
        aq[it] = *(const bf16x8*)&Qg[((it * 4 + wave) * 16 + lm) * 32 + lq * 8];
    __syncthreads();

    f32x4 o[6][2] = {};
    float ls[6] = {0.f, 0.f, 0.f, 0.f, 0.f, 0.f};

    for (int n0 = 0; n0 < 384; n0 += 32) {
        bf16x8 kf0 = *(const bf16x8*)&Ks[(n0 + lm) * 32 + lq * 8];
        bf16x8 kf1 = *(const bf16x8*)&Ks[(n0 + 16 + lm) * 32 + lq * 8];
        s16x4 vf00 = *(const s16x4*)&Vt[lm * 392 + n0 + lq * 4];
        s16x4 vf01 = *(const s16x4*)&Vt[lm * 392 + n0 + 16 + lq * 4];
        s16x4 vf10 = *(const s16x4*)&Vt[(16 + lm) * 392 + n0 + lq * 4];
        s16x4 vf11 = *(const s16x4*)&Vt[(16 + lm) * 392 + n0 + 16 + lq * 4];
        #pragma unroll
        for (int it = 0; it < 6; ++it) {
            f32x4 z = {0.f, 0.f, 0.f, 0.f};
            f32x4 s0 = __builtin_amdgcn_mfma_f32_16x16x32_bf16(kf0, aq[it], z, 0, 0, 0);
            f32x4 s1 = __builtin_amdgcn_mfma_f32_16x16x32_bf16(kf1, aq[it], z, 0, 0, 0);
            float p0[4], p1[4];
            float a = 0.f;
            #pragma unroll
            for (int r = 0; r < 4; ++r) {
                p0[r] = __builtin_amdgcn_exp2f(s0[r]);
                p1[r] = __builtin_amdgcn_exp2f(s1[r]);
                a += tbf(p0[r]) + tbf(p1[r]);
            }
            ls[it] += a;
            union { s16x4 v; uint2 u; } pk0, pk1;
            pk0.u.x = __builtin_amdgcn_perm(__float_as_uint(p0[1]), __float_as_uint(p0[0]), 0x07060302u);
            pk0.u.y = __builtin_amdgcn_perm(__float_as_uint(p0[3]), __float_as_uint(p0[2]), 0x07060302u);
            pk1.u.x = __builtin_amdgcn_perm(__float_as_uint(p1[1]), __float_as_uint(p1[0]), 0x07060302u);
            pk1.u.y = __builtin_amdgcn_perm(__float_as_uint(p1[3]), __float_as_uint(p1[2]), 0x07060302u);
            o[it][0] = pv_mfma(vf00, pk0.v, o[it][0]);
            o[it][0] = pv_mfma(vf01, pk1.v, o[it][0]);
            o[it][1] = pv_mfma(vf10, pk0.v, o[it][1]);
            o[it][1] = pv_mfma(vf11, pk1.v, o[it][1]);
        }
    }

    #pragma unroll
    for (int it = 0; it < 6; ++it) {
        float L = ls[it];
        L += __shfl_xor(L, 16, 64);
        L += __shfl_xor(L, 32, 64);
        float inv = __builtin_amdgcn_rcpf(L);
        int l = (it * 4 + wave) * 16 + lm;
        int base = (s * 384 + l) * 256 + h * 32 + lq * 4;
        #pragma unroll
        for (int dt = 0; dt < 2; ++dt) {
            ushort4 oh, ol;
            float x0 = o[it][dt][0] * inv, x1 = o[it][dt][1] * inv;
            float x2 = o[it][dt][2] * inv, x3 = o[it][dt][3] * inv;
            oh.x = f2bf(x0); ol.x = f2bf(x0 - bf2f(oh.x));
            oh.y = f2bf(x1); ol.y = f2bf(x1 - bf2f(oh.y));
            oh.z = f2bf(x2); ol.z = f2bf(x2 - bf2f(oh.z));
            oh.w = f2bf(x3); ol.w = f2bf(x3 - bf2f(oh.w));
            *(ushort4*)&Ahi[base + dt * 16] = oh;
            *(ushort4*)&Alo[base + dt * 16] = ol;
        }
    }
}

// ---------------------------------------------------------------- output GEMM
// Transposed orientation: out^T tiles, r -> feature contiguous -> float4 stores.
__launch_bounds__(256, 2)
__global__ void out_gemm(const u16* __restrict__ Ahi, const u16* __restrict__ Alo,
                         const u16* __restrict__ Woh, const u16* __restrict__ Wol,
                         float* __restrict__ out) {
    __shared__ __align__(16) u16 Ah[128 * 32], Al[128 * 32], Bh[128 * 32], Bl[128 * 32];
    const int tid = threadIdx.x;
    const int tm = blockIdx.x % 384, tn = blockIdx.x / 384;   // grid 768, tn in {0,1}
    const int lane = tid & 63, wave = tid >> 6;
    const int lm = lane & 15, lq = lane >> 4;
    const int wm = (wave >> 1) * 64, wn = (wave & 1) * 64;
    f32x4 acc[4][4] = {};

    const int ra = tid >> 2, ka = (tid & 3) << 3;
    const int rb = ra + 64;

    for (int k0 = 0; k0 < 256; k0 += 32) {
        *(uint4*)&Ah[ra * 32 + ka] = *(const uint4*)&Ahi[(tm * 128 + ra) * 256 + k0 + ka];
        *(uint4*)&Ah[rb * 32 + ka] = *(const uint4*)&Ahi[(tm * 128 + rb) * 256 + k0 + ka];
        *(uint4*)&Al[ra * 32 + ka] = *(const uint4*)&Alo[(tm * 128 + ra) * 256 + k0 + ka];
        *(uint4*)&Al[rb * 32 + ka] = *(const uint4*)&Alo[(tm * 128 + rb) * 256 + k0 + ka];
        *(uint4*)&Bh[ra * 32 + ka] = *(const uint4*)&Woh[(tn * 128 + ra) * 256 + k0 + ka];
        *(uint4*)&Bh[rb * 32 + ka] = *(const uint4*)&Woh[(tn * 128 + rb) * 256 + k0 + ka];
        *(uint4*)&Bl[ra * 32 + ka] = *(const uint4*)&Wol[(tn * 128 + ra) * 256 + k0 + ka];
        *(uint4*)&Bl[rb * 32 + ka] = *(const uint4*)&Wol[(tn * 128 + rb) * 256 + k0 + ka];
        __syncthreads();
        bf16x8 whf[4], wlf[4], ahf[4], alf[4];
        #pragma unroll
        for (int i = 0; i < 4; ++i) {
            whf[i] = *(const bf16x8*)&Bh[(wm + i * 16 + lm) * 32 + lq * 8];
            wlf[i] = *(const bf16x8*)&Bl[(wm + i * 16 + lm) * 32 + lq * 8];
        }
        #pragma unroll
        for (int j = 0; j < 4; ++j) {
            ahf[j] = *(const bf16x8*)&Ah[(wn + j * 16 + lm) * 32 + lq * 8];
            alf[j] = *(const bf16x8*)&Al[(wn + j * 16 + lm) * 32 + lq * 8];
        }
        #pragma unroll
        for (int i = 0; i < 4; ++i)
            #pragma unroll
            for (int j = 0; j < 4; ++j) {
                acc[i][j] = __builtin_amdgcn_mfma_f32_16x16x32_bf16(whf[i], alf[j], acc[i][j], 0, 0, 0);
                acc[i][j] = __builtin_amdgcn_mfma_f32_16x16x32_bf16(wlf[i], ahf[j], acc[i][j], 0, 0, 0);
                acc[i][j] = __builtin_amdgcn_mfma_f32_16x16x32_bf16(whf[i], ahf[j], acc[i][j], 0, 0, 0);
            }
        __syncthreads();
    }
    #pragma unroll
    for (int i = 0; i < 4; ++i) {
        int F0 = tn * 128 + wm + i * 16 + lq * 4;
        #pragma unroll
        for (int j = 0; j < 4; ++j) {
            int R = tm * 128 + wn + j * 16 + lm;
            *(f32x4*)&out[R * 256 + F0] = acc[i][j];
        }
    }
}

// ---------------------------------------------------------------- launch
extern "C" void kernel_launch(void* const* d_in, const int* in_sizes, int n_in,
                              void* d_out, int out_size, void* d_ws, size_t ws_size,
                              hipStream_t stream) {
    const float* msa = (const float*)d_in[0];
    const float* Wq = (const float*)d_in[2];
    const float* Wk = (const float*)d_in[3];
    const float* Wv = (const float*)d_in[4];
    const float* Wo = (const float*)d_in[5];
    char* ws = (char*)d_ws;
    u16* msa_bf = (u16*)(ws + 0);              // 25165824 B
    u16* Qb     = (u16*)(ws + 25165824);       // 25165824 B  [sh][l][d], pre-scaled
    u16* Kb     = (u16*)(ws + 50331648);       // 25165824 B  [sh][l][d]
    u16* VTb    = (u16*)(ws + 75497472);       // 25165824 B  [sh][d][l]
    u16* Ahi    = (u16*)(ws + 100663296);      // 25165824 B
    u16* Alo    = (u16*)(ws + 125829120);      // 25165824 B
    u16* Wqkv   = (u16*)(ws + 150994944);      // 393216 B
    u16* Woh    = (u16*)(ws + 151388160);      // 131072 B
    u16* Wol    = (u16*)(ws + 151519232);      // 131072 B
    float* out  = (float*)d_out;

    hipLaunchKernelGGL(convert_msa, dim3(12288), dim3(256), 0, stream, msa, msa_bf);
    hipLaunchKernelGGL(pack_weights, dim3(256), dim3(256), 0, stream, Wq, Wk, Wv, Wo, Wqkv, Woh, Wol);
    hipLaunchKernelGGL(qkv_gemm, dim3(2304), dim3(256), 0, stream, msa_bf, Wqkv, Qb, Kb, VTb);
    hipLaunchKernelGGL(msa_attention, dim3(1024), dim3(256), 0, stream, Qb, Kb, VTb, Ahi, Alo);
    hipLaunchKernelGGL(out_gemm, dim3(768), dim3(256), 0, stream, Ahi, Alo, Woh, Wol, out);
}

// Round 3
// 264.836 us; speedup vs baseline: 1.1065x; 1.0710x over previous
//
#include <hip/hip_runtime.h>
#include <stdint.h>

typedef unsigned short u16;
typedef __bf16 bf16x8 __attribute__((ext_vector_type(8)));
typedef short s16x4 __attribute__((ext_vector_type(4)));
typedef float f32x4 __attribute__((ext_vector_type(4)));

#define QKV_STRIDE 12288    // per (s,h): 384 * 32

__device__ __forceinline__ u16 f2bf(float x) {
    unsigned int u = __float_as_uint(x);
    u += 0x7fffu + ((u >> 16) & 1u);
    return (u16)(u >> 16);
}
__device__ __forceinline__ float bf2f(u16 h) {
    return __uint_as_float(((unsigned int)h) << 16);
}

// async global->LDS, 16B per lane; lds dest is wave-uniform base + lane*16
__device__ __forceinline__ void async_copy16(const u16* g, u16* l) {
    __builtin_amdgcn_global_load_lds(
        (const __attribute__((address_space(1))) unsigned int*)g,
        (__attribute__((address_space(3))) unsigned int*)l, 16, 0, 0);
}

// PV matmul: 16x16x16 bf16 (P^T C-frag is directly a valid B-frag).
static __device__ __forceinline__ f32x4 pv_mfma(s16x4 a, s16x4 b, f32x4 c) {
#if __has_builtin(__builtin_amdgcn_mfma_f32_16x16x16bf16_1k)
    return __builtin_amdgcn_mfma_f32_16x16x16bf16_1k(a, b, c, 0, 0, 0);
#else
    union { s16x4 h[2]; bf16x8 v; } ua, ub;
    s16x4 zz = {0, 0, 0, 0};
    ua.h[0] = a; ua.h[1] = zz;
    ub.h[0] = b; ub.h[1] = zz;
    return __builtin_amdgcn_mfma_f32_16x16x32_bf16(ua.v, ub.v, c, 0, 0, 0);
#endif
}

// ------------------------------------------------- prep: convert msa + pack W
__global__ void prep(const float* __restrict__ msa,
                     const float* __restrict__ Wq, const float* __restrict__ Wk,
                     const float* __restrict__ Wv, const float* __restrict__ Wo,
                     u16* __restrict__ msa_bf, u16* __restrict__ Wqkv,
                     u16* __restrict__ Woh, u16* __restrict__ Wol) {
    int b = blockIdx.x;
    if (b < 12288) {
        int i = b * 256 + threadIdx.x;
        float4 v = ((const float4*)msa)[i];
        ushort4 o;
        o.x = f2bf(v.x); o.y = f2bf(v.y); o.z = f2bf(v.z); o.w = f2bf(v.w);
        ((ushort4*)msa_bf)[i] = o;
    } else {
        int i = (b - 12288) * 256 + threadIdx.x;     // 65536 total
        Wqkv[i]          = f2bf(Wq[i]);
        Wqkv[65536 + i]  = f2bf(Wk[i]);
        Wqkv[131072 + i] = f2bf(Wv[i]);
        float w = Wo[i];
        u16 hi = f2bf(w);
        Woh[i] = hi;
        Wol[i] = f2bf(w - bf2f(hi));
    }
}

// ---------------------------------------------------------------- QKV GEMM
// tn<4 (Q,K): transposed orientation, packed [sh][l][d] stores (Q pre-scaled).
// tn>=4 (V): normal orientation, packed V^T [sh][d][l] stores.
__launch_bounds__(256, 2)
__global__ void qkv_gemm(const u16* __restrict__ A, const u16* __restrict__ W,
                         u16* __restrict__ Qb, u16* __restrict__ Kb, u16* __restrict__ VTb) {
    __shared__ __align__(16) u16 As[128 * 32];
    __shared__ __align__(16) u16 Bs[128 * 32];
    const int tid = threadIdx.x;
    const int tm = blockIdx.x % 384, tn = blockIdx.x / 384;   // grid 2304
    const bool trans = (tn < 4);
    const int lane = tid & 63, wave = tid >> 6;
    const int lm = lane & 15, lq = lane >> 4;
    const int wm = (wave >> 1) * 64, wn = (wave & 1) * 64;
    const float CEXPF = 0.17677669529663687f * 1.4426950408889634f;
    f32x4 acc[4][4] = {};

    // async staging geometry: lane deposits 16B at (wave*1024 + lane*16) bytes
    const int srow = wave * 16 + (lane >> 2);
    const int scol = (lane & 3) * 8;
    u16* ldsA0 = &As[wave * 512 + lane * 8];
    u16* ldsA1 = &As[2048 + wave * 512 + lane * 8];
    u16* ldsB0 = &Bs[wave * 512 + lane * 8];
    u16* ldsB1 = &Bs[2048 + wave * 512 + lane * 8];
    const u16* gA0 = &A[(tm * 128 + srow) * 256 + scol];
    const u16* gA1 = &A[(tm * 128 + 64 + srow) * 256 + scol];
    const u16* gB0 = &W[(tn * 128 + srow) * 256 + scol];
    const u16* gB1 = &W[(tn * 128 + 64 + srow) * 256 + scol];

    for (int k0 = 0; k0 < 256; k0 += 32) {
        async_copy16(gA0 + k0, ldsA0);
        async_copy16(gA1 + k0, ldsA1);
        async_copy16(gB0 + k0, ldsB0);
        async_copy16(gB1 + k0, ldsB1);
        __syncthreads();
        const u16* Xs = trans ? Bs : As;   // A-operand (m dim)
        const u16* Ys = trans ? As : Bs;   // B-operand (n dim)
        bf16x8 xf[4], yf[4];
        #pragma unroll
        for (int i = 0; i < 4; ++i)
            xf[i] = *(const bf16x8*)&Xs[(wm + i * 16 + lm) * 32 + lq * 8];
        #pragma unroll
        for (int j = 0; j < 4; ++j)
            yf[j] = *(const bf16x8*)&Ys[(wn + j * 16 + lm) * 32 + lq * 8];
        #pragma unroll
        for (int i = 0; i < 4; ++i)
            #pragma unroll
            for (int j = 0; j < 4; ++j)
                acc[i][j] = __builtin_amdgcn_mfma_f32_16x16x32_bf16(xf[i], yf[j], acc[i][j], 0, 0, 0);
        __syncthreads();
    }

    if (trans) {
        // m = feature F (r -> d contiguous), n = msa row R
        #pragma unroll
        for (int i = 0; i < 4; ++i) {
            int F0 = tn * 128 + wm + i * 16 + lq * 4;
            int which = F0 >> 8;                 // 0=Q, 1=K
            int h = (F0 >> 5) & 7, d0 = F0 & 31;
            u16* dst = which ? Kb : Qb;
            float scale = which ? 1.0f : CEXPF;
            #pragma unroll
            for (int j = 0; j < 4; ++j) {
                int R = tm * 128 + wn + j * 16 + lm;
                int s = R / 384, l = R - s * 384;
                ushort4 o;
                o.x = f2bf(acc[i][j][0] * scale);
                o.y = f2bf(acc[i][j][1] * scale);
                o.z = f2bf(acc[i][j][2] * scale);
                o.w = f2bf(acc[i][j][3] * scale);
                *(ushort4*)&dst[((s * 8 + h) * 384 + l) * 32 + d0] = o;
            }
        }
    } else {
        // m = msa row R (r -> l contiguous), n = feature F in [512,768)
        #pragma unroll
        for (int j = 0; j < 4; ++j) {
            int F = tn * 128 + wn + j * 16 + lm;
            int h = (F >> 5) & 7, d = F & 31;
            #pragma unroll
            for (int i = 0; i < 4; ++i) {
                int R0 = tm * 128 + wm + i * 16 + lq * 4;
                int s = R0 / 384, l0 = R0 - s * 384;
                ushort4 o;
                o.x = f2bf(acc[i][j][0]);
                o.y = f2bf(acc[i][j][1]);
                o.z = f2bf(acc[i][j][2]);
                o.w = f2bf(acc[i][j][3]);
                *(ushort4*)&VTb[((s * 8 + h) * 32 + d) * 384 + l0] = o;
            }
        }
    }
}

// ---------------------------------------------------------------- attention
// Grid 3072: block = (s,h, l-part of 128). V^T in LDS (25 KB -> 6 blocks/CU);
// K read per-wave from global (coalesced b128, LLC-resident). S^T = K*Q^T;
// its C-frag feeds 16x16x16 PV directly. l = 1^T*P via a ones-MFMA (exact sum
// of stored truncated P -> truncation cancels in the ratio).
__launch_bounds__(256, 6)
__global__ void msa_attention(const u16* __restrict__ Qb, const u16* __restrict__ Kb,
                              const u16* __restrict__ VTb,
                              u16* __restrict__ Ahi, u16* __restrict__ Alo) {
    __shared__ __align__(16) u16 Vt[32 * 392];   // 25088 B (V^T rows, stride 392)
    const int tid = threadIdx.x;
    const int bid = blockIdx.x;                   // 3072 blocks
    const int sh = bid / 3, lpart = bid - sh * 3;
    const int s = sh >> 3, h = sh & 7;
    const u16* Qg = Qb + (size_t)sh * QKV_STRIDE;
    const u16* Kg = Kb + (size_t)sh * QKV_STRIDE;
    const u16* Vg = VTb + (size_t)sh * QKV_STRIDE;

    for (int i = tid; i < 1536; i += 256) {
        int d = i / 48, c = i - d * 48;
        *(uint4*)&Vt[d * 392 + c * 8] = *(const uint4*)&Vg[d * 384 + c * 8];
    }

    const int lane = tid & 63, wave = tid >> 6;
    const int lm = lane & 15, lq = lane >> 4;

    bf16x8 aq[2];
    #pragma unroll
    for (int it = 0; it < 2; ++it) {
        int l = lpart * 128 + (wave * 2 + it) * 16 + lm;
        aq[it] = *(const bf16x8*)&Qg[l * 32 + lq * 8];
    }
    __syncthreads();

    f32x4 o[2][2] = {};
    f32x4 lacc[2] = {};
    const s16x4 ones = {(short)0x3F80, (short)0x3F80, (short)0x3F80, (short)0x3F80};

    for (int n0 = 0; n0 < 384; n0 += 32) {
        bf16x8 kf0 = *(const bf16x8*)&Kg[(n0 + lm) * 32 + lq * 8];
        bf16x8 kf1 = *(const bf16x8*)&Kg[(n0 + 16 + lm) * 32 + lq * 8];
        s16x4 vf00 = *(const s16x4*)&Vt[lm * 392 + n0 + lq * 4];
        s16x4 vf01 = *(const s16x4*)&Vt[lm * 392 + n0 + 16 + lq * 4];
        s16x4 vf10 = *(const s16x4*)&Vt[(16 + lm) * 392 + n0 + lq * 4];
        s16x4 vf11 = *(const s16x4*)&Vt[(16 + lm) * 392 + n0 + 16 + lq * 4];
        #pragma unroll
        for (int it = 0; it < 2; ++it) {
            f32x4 z = {0.f, 0.f, 0.f, 0.f};
            f32x4 s0 = __builtin_amdgcn_mfma_f32_16x16x32_bf16(kf0, aq[it], z, 0, 0, 0);
            f32x4 s1 = __builtin_amdgcn_mfma_f32_16x16x32_bf16(kf1, aq[it], z, 0, 0, 0);
            float p0[4], p1[4];
            #pragma unroll
            for (int r = 0; r < 4; ++r) {
                p0[r] = __builtin_amdgcn_exp2f(s0[r]);
                p1[r] = __builtin_amdgcn_exp2f(s1[r]);
            }
            union { s16x4 v; uint2 u; } pk0, pk1;
            pk0.u.x = __builtin_amdgcn_perm(__float_as_uint(p0[1]), __float_as_uint(p0[0]), 0x07060302u);
            pk0.u.y = __builtin_amdgcn_perm(__float_as_uint(p0[3]), __float_as_uint(p0[2]), 0x07060302u);
            pk1.u.x = __builtin_amdgcn_perm(__float_as_uint(p1[1]), __float_as_uint(p1[0]), 0x07060302u);
            pk1.u.y = __builtin_amdgcn_perm(__float_as_uint(p1[3]), __float_as_uint(p1[2]), 0x07060302u);
            o[it][0] = pv_mfma(vf00, pk0.v, o[it][0]);
            o[it][0] = pv_mfma(vf01, pk1.v, o[it][0]);
            o[it][1] = pv_mfma(vf10, pk0.v, o[it][1]);
            o[it][1] = pv_mfma(vf11, pk1.v, o[it][1]);
            lacc[it] = pv_mfma(ones, pk0.v, lacc[it]);
            lacc[it] = pv_mfma(ones, pk1.v, lacc[it]);
        }
    }

    #pragma unroll
    for (int it = 0; it < 2; ++it) {
        float inv = __builtin_amdgcn_rcpf(lacc[it][0]);
        int l = lpart * 128 + (wave * 2 + it) * 16 + lm;
        int base = (s * 384 + l) * 256 + h * 32 + lq * 4;
        #pragma unroll
        for (int dt = 0; dt < 2; ++dt) {
            ushort4 oh, ol;
            float x0 = o[it][dt][0] * inv, x1 = o[it][dt][1] * inv;
            float x2 = o[it][dt][2] * inv, x3 = o[it][dt][3] * inv;
            oh.x = f2bf(x0); ol.x = f2bf(x0 - bf2f(oh.x));
            oh.y = f2bf(x1); ol.y = f2bf(x1 - bf2f(oh.y));
            oh.z = f2bf(x2); ol.z = f2bf(x2 - bf2f(oh.z));
            oh.w = f2bf(x3); ol.w = f2bf(x3 - bf2f(oh.w));
            *(ushort4*)&Ahi[base + dt * 16] = oh;
            *(ushort4*)&Alo[base + dt * 16] = ol;
        }
    }
}

// ---------------------------------------------------------------- output GEMM
// Transposed orientation: out^T tiles, r -> feature contiguous -> float4 stores.
__launch_bounds__(256, 2)
__global__ void out_gemm(const u16* __restrict__ Ahi, const u16* __restrict__ Alo,
                         const u16* __restrict__ Woh, const u16* __restrict__ Wol,
                         float* __restrict__ out) {
    __shared__ __align__(16) u16 Ah[128 * 32], Al[128 * 32], Bh[128 * 32], Bl[128 * 32];
    const int tid = threadIdx.x;
    const int tm = blockIdx.x % 384, tn = blockIdx.x / 384;   // grid 768, tn in {0,1}
    const int lane = tid & 63, wave = tid >> 6;
    const int lm = lane & 15, lq = lane >> 4;
    const int wm = (wave >> 1) * 64, wn = (wave & 1) * 64;
    f32x4 acc[4][4] = {};

    const int srow = wave * 16 + (lane >> 2);
    const int scol = (lane & 3) * 8;
    const int lo0 = wave * 512 + lane * 8, lo1 = 2048 + wave * 512 + lane * 8;
    const u16* gAh0 = &Ahi[(tm * 128 + srow) * 256 + scol];
    const u16* gAh1 = &Ahi[(tm * 128 + 64 + srow) * 256 + scol];
    const u16* gAl0 = &Alo[(tm * 128 + srow) * 256 + scol];
    const u16* gAl1 = &Alo[(tm * 128 + 64 + srow) * 256 + scol];
    const u16* gBh0 = &Woh[(tn * 128 + srow) * 256 + scol];
    const u16* gBh1 = &Woh[(tn * 128 + 64 + srow) * 256 + scol];
    const u16* gBl0 = &Wol[(tn * 128 + srow) * 256 + scol];
    const u16* gBl1 = &Wol[(tn * 128 + 64 + srow) * 256 + scol];

    for (int k0 = 0; k0 < 256; k0 += 32) {
        async_copy16(gAh0 + k0, &Ah[lo0]);
        async_copy16(gAh1 + k0, &Ah[lo1]);
        async_copy16(gAl0 + k0, &Al[lo0]);
        async_copy16(gAl1 + k0, &Al[lo1]);
        async_copy16(gBh0 + k0, &Bh[lo0]);
        async_copy16(gBh1 + k0, &Bh[lo1]);
        async_copy16(gBl0 + k0, &Bl[lo0]);
        async_copy16(gBl1 + k0, &Bl[lo1]);
        __syncthreads();
        bf16x8 whf[4], wlf[4], ahf[4], alf[4];
        #pragma unroll
        for (int i = 0; i < 4; ++i) {
            whf[i] = *(const bf16x8*)&Bh[(wm + i * 16 + lm) * 32 + lq * 8];
            wlf[i] = *(const bf16x8*)&Bl[(wm + i * 16 + lm) * 32 + lq * 8];
        }
        #pragma unroll
        for (int j = 0; j < 4; ++j) {
            ahf[j] = *(const bf16x8*)&Ah[(wn + j * 16 + lm) * 32 + lq * 8];
            alf[j] = *(const bf16x8*)&Al[(wn + j * 16 + lm) * 32 + lq * 8];
        }
        #pragma unroll
        for (int i = 0; i < 4; ++i)
            #pragma unroll
            for (int j = 0; j < 4; ++j) {
                acc[i][j] = __builtin_amdgcn_mfma_f32_16x16x32_bf16(whf[i], alf[j], acc[i][j], 0, 0, 0);
                acc[i][j] = __builtin_amdgcn_mfma_f32_16x16x32_bf16(wlf[i], ahf[j], acc[i][j], 0, 0, 0);
                acc[i][j] = __builtin_amdgcn_mfma_f32_16x16x32_bf16(whf[i], ahf[j], acc[i][j], 0, 0, 0);
            }
        __syncthreads();
    }
    #pragma unroll
    for (int i = 0; i < 4; ++i) {
        int F0 = tn * 128 + wm + i * 16 + lq * 4;
        #pragma unroll
        for (int j = 0; j < 4; ++j) {
            int R = tm * 128 + wn + j * 16 + lm;
            *(f32x4*)&out[R * 256 + F0] = acc[i][j];
        }
    }
}

// ---------------------------------------------------------------- launch
extern "C" void kernel_launch(void* const* d_in, const int* in_sizes, int n_in,
                              void* d_out, int out_size, void* d_ws, size_t ws_size,
                              hipStream_t stream) {
    const float* msa = (const float*)d_in[0];
    const float* Wq = (const float*)d_in[2];
    const float* Wk = (const float*)d_in[3];
    const float* Wv = (const float*)d_in[4];
    const float* Wo = (const float*)d_in[5];
    char* ws = (char*)d_ws;
    u16* msa_bf = (u16*)(ws + 0);              // 25165824 B
    u16* Qb     = (u16*)(ws + 25165824);       // 25165824 B  [sh][l][d], pre-scaled
    u16* Kb     = (u16*)(ws + 50331648);       // 25165824 B  [sh][l][d]
    u16* VTb    = (u16*)(ws + 75497472);       // 25165824 B  [sh][d][l]
    u16* Ahi    = (u16*)(ws + 100663296);      // 25165824 B
    u16* Alo    = (u16*)(ws + 125829120);      // 25165824 B
    u16* Wqkv   = (u16*)(ws + 150994944);      // 393216 B
    u16* Woh    = (u16*)(ws + 151388160);      // 131072 B
    u16* Wol    = (u16*)(ws + 151519232);      // 131072 B
    float* out  = (float*)d_out;

    hipLaunchKernelGGL(prep, dim3(12544), dim3(256), 0, stream, msa, Wq, Wk, Wv, Wo,
                       msa_bf, Wqkv, Woh, Wol);
    hipLaunchKernelGGL(qkv_gemm, dim3(2304), dim3(256), 0, stream, msa_bf, Wqkv, Qb, Kb, VTb);
    hipLaunchKernelGGL(msa_attention, dim3(3072), dim3(256), 0, stream, Qb, Kb, VTb, Ahi, Alo);
    hipLaunchKernelGGL(out_gemm, dim3(768), dim3(256), 0, stream, Ahi, Alo, Woh, Wol, out);
}